// Round 2
// baseline (840.376 us; speedup 1.0000x reference)
//
#include <hip/hip_runtime.h>
#include <math.h>

#define TT 512
#define BB 512
#define FF 14
#define H1 32
#define H2 64
#define G1 128   // 4*H1
#define G2 256   // 4*H2

__device__ __forceinline__ float sigmoidf_(float x) {
    return 1.0f / (1.0f + __expf(-x));
}
__device__ __forceinline__ float tanhf_(float x) {
    float e = __expf(-2.0f * fabsf(x));
    float t = (1.0f - e) / (1.0f + e);
    return copysignf(t, x);
}

// One block per batch row, 256 threads (4 waves), 2 blocks/CU.
// Weights in VGPRs: thread t owns layer-2 gate t (96 floats as float4);
// threads 128..255 additionally own layer-1 gate t-128 (48 floats).
// LDS holds only state (h1, h2, gates, x double-buffer). 3 barriers/step.
__global__ __launch_bounds__(256, 2) void lstm3_kernel(
    const float* __restrict__ x,
    const float* __restrict__ Wih1, const float* __restrict__ Whh1,
    const float* __restrict__ bih1, const float* __restrict__ bhh1,
    const float* __restrict__ Wih2, const float* __restrict__ Whh2,
    const float* __restrict__ bih2, const float* __restrict__ bhh2,
    const float* __restrict__ Wfc1, const float* __restrict__ bfc1,
    const float* __restrict__ Wfc2, const float* __restrict__ bfc2,
    const float* __restrict__ Wfc,  const float* __restrict__ bfc,
    float* __restrict__ out)
{
    const int row = blockIdx.x;
    const int t   = threadIdx.x;

    __shared__ __align__(16) float xbuf[2][16];   // x_t double buffer (14 used + 2 zero pad)
    __shared__ __align__(16) float h1s[H1];
    __shared__ __align__(16) float h2s[H2];
    __shared__ float g1buf[G1];
    __shared__ float g2buf[G2];
    __shared__ float mlp1[8];
    __shared__ float mlp2[8];

    // ---- layer-2 weights for gate t, as float4 (rows are 128B/256B aligned) ----
    float4 w2a[8];    // Wih2 row t: 32 floats
    float4 w2b[16];   // Whh2 row t: 64 floats
    {
        const float4* p = (const float4*)(Wih2 + t * H1);
        #pragma unroll
        for (int k = 0; k < 8; ++k) w2a[k] = p[k];
        const float4* q = (const float4*)(Whh2 + t * H2);
        #pragma unroll
        for (int k = 0; k < 16; ++k) w2b[k] = q[k];
    }
    const float b2r = bih2[t] + bhh2[t];

    // ---- layer-1 weights for gate t-128 (threads 128..255) ----
    // w1[0..13] = Wih1 row, w1[14..15] = 0 (pad), w1[16..47] = Whh1 row
    float w1[48];
    float b1r = 0.0f;
    if (t >= 128) {
        const int g = t - 128;
        #pragma unroll
        for (int k = 0; k < FF; ++k) w1[k] = Wih1[g * FF + k];
        w1[14] = 0.0f; w1[15] = 0.0f;
        const float4* q = (const float4*)(Whh1 + g * H1);
        #pragma unroll
        for (int k = 0; k < 8; ++k) {
            float4 v = q[k];
            w1[16 + 4 * k + 0] = v.x; w1[16 + 4 * k + 1] = v.y;
            w1[16 + 4 * k + 2] = v.z; w1[16 + 4 * k + 3] = v.w;
        }
        b1r = bih1[g] + bhh1[g];
    }

    float c1r = 0.0f;   // layer-1 cell state, owned by threads 0..31
    float xreg = 0.0f;  // x prefetch register, threads 64..77

    // ---- init state, stage x[0], prefetch x[1] ----
    if (t < H1) h1s[t] = 0.0f;
    if (t < H2) h2s[t] = 0.0f;
    if (t >= 64 && t < 64 + FF) {
        const int f = t - 64;
        xbuf[0][f] = x[(size_t)0 * BB * FF + row * FF + f];
        xreg       = x[(size_t)1 * BB * FF + row * FF + f];
    }
    if (t == 78) { xbuf[0][14] = 0.f; xbuf[0][15] = 0.f; xbuf[1][14] = 0.f; xbuf[1][15] = 0.f; }
    __syncthreads();

    for (int step = 0; step < TT; ++step) {
        // ================= Phase A =================
        // threads 128..255: layer-1 gates (read xbuf[step&1], h1s)
        // threads   0..63 : h2 update of previous step (reads g2buf) [step>0]
        // threads  64..77 : stage xbuf[(step+1)&1], prefetch next x
        if (t >= 128) {
            const float4* xv  = (const float4*)xbuf[step & 1];
            const float4* h1v = (const float4*)h1s;
            float a0 = b1r, a1 = 0.f, a2 = 0.f, a3 = 0.f;
            #pragma unroll
            for (int k = 0; k < 4; ++k) {
                float4 v = xv[k];
                a0 = fmaf(v.x, w1[4 * k + 0], a0);
                a1 = fmaf(v.y, w1[4 * k + 1], a1);
                a2 = fmaf(v.z, w1[4 * k + 2], a2);
                a3 = fmaf(v.w, w1[4 * k + 3], a3);
            }
            #pragma unroll
            for (int k = 0; k < 8; ++k) {
                float4 v = h1v[k];
                a0 = fmaf(v.x, w1[16 + 4 * k + 0], a0);
                a1 = fmaf(v.y, w1[16 + 4 * k + 1], a1);
                a2 = fmaf(v.z, w1[16 + 4 * k + 2], a2);
                a3 = fmaf(v.w, w1[16 + 4 * k + 3], a3);
            }
            g1buf[t - 128] = (a0 + a1) + (a2 + a3);
        } else if (t < H2) {
            if (step > 0) {
                const float ig = g2buf[t];
                const float gg = g2buf[t + 128];
                const float og = g2buf[t + 192];
                const float cn = sigmoidf_(ig) * tanhf_(gg);
                h2s[t] = sigmoidf_(og) * tanhf_(cn);
            }
        } else if (t < 64 + FF) {
            const int f = t - 64;
            xbuf[(step + 1) & 1][f] = xreg;
            const int tn = (step + 2 < TT) ? (step + 2) : (TT - 1);
            xreg = x[(size_t)tn * BB * FF + row * FF + f];
        }
        __syncthreads();

        // ================= Phase B: h1/c1 update (threads 0..31) =================
        if (t < H1) {
            const float ig = g1buf[t];
            const float fg = g1buf[t + 32];
            const float gg = g1buf[t + 64];
            const float og = g1buf[t + 96];
            const float cn = sigmoidf_(fg) * c1r + sigmoidf_(ig) * tanhf_(gg);
            c1r = cn;
            h1s[t] = sigmoidf_(og) * tanhf_(cn);
        }
        __syncthreads();

        // ================= Phase C: layer-2 gates (all 256 threads) =================
        {
            const float4* h1v = (const float4*)h1s;
            const float4* h2v = (const float4*)h2s;
            float a0 = b2r, a1 = 0.f, a2 = 0.f, a3 = 0.f;
            #pragma unroll
            for (int k = 0; k < 8; ++k) {
                float4 v = h1v[k];
                a0 = fmaf(v.x, w2a[k].x, a0);
                a1 = fmaf(v.y, w2a[k].y, a1);
                a2 = fmaf(v.z, w2a[k].z, a2);
                a3 = fmaf(v.w, w2a[k].w, a3);
            }
            #pragma unroll
            for (int k = 0; k < 16; ++k) {
                float4 v = h2v[k];
                a0 = fmaf(v.x, w2b[k].x, a0);
                a1 = fmaf(v.y, w2b[k].y, a1);
                a2 = fmaf(v.z, w2b[k].z, a2);
                a3 = fmaf(v.w, w2b[k].w, a3);
            }
            g2buf[t] = (a0 + a1) + (a2 + a3);
        }
        __syncthreads();
    }

    // ---- final h2 update (for step TT-1) ----
    if (t < H2) {
        const float ig = g2buf[t];
        const float gg = g2buf[t + 128];
        const float og = g2buf[t + 192];
        const float cn = sigmoidf_(ig) * tanhf_(gg);
        h2s[t] = sigmoidf_(og) * tanhf_(cn);
    }
    __syncthreads();

    // ---- MLP head ----
    if (t < 8) {
        float a = bfc1[t];
        #pragma unroll
        for (int k = 0; k < H2; ++k)
            a = fmaf(fmaxf(h2s[k], 0.0f), Wfc1[t * H2 + k], a);
        mlp1[t] = fmaxf(a, 0.0f);
    }
    __syncthreads();
    if (t < 8) {
        float a = bfc2[t];
        #pragma unroll
        for (int k = 0; k < 8; ++k) a = fmaf(mlp1[k], Wfc2[t * 8 + k], a);
        mlp2[t] = fmaxf(a, 0.0f);
    }
    __syncthreads();
    if (t == 0) {
        float a = bfc[0];
        #pragma unroll
        for (int k = 0; k < 8; ++k) a = fmaf(mlp2[k], Wfc[k], a);
        out[row] = a;
    }
}

extern "C" void kernel_launch(void* const* d_in, const int* in_sizes, int n_in,
                              void* d_out, int out_size, void* d_ws, size_t ws_size,
                              hipStream_t stream) {
    const float* x    = (const float*)d_in[0];
    const float* Wih1 = (const float*)d_in[1];
    const float* Whh1 = (const float*)d_in[2];
    const float* bih1 = (const float*)d_in[3];
    const float* bhh1 = (const float*)d_in[4];
    const float* Wih2 = (const float*)d_in[5];
    const float* Whh2 = (const float*)d_in[6];
    const float* bih2 = (const float*)d_in[7];
    const float* bhh2 = (const float*)d_in[8];
    const float* Wfc1 = (const float*)d_in[9];
    const float* bfc1 = (const float*)d_in[10];
    const float* Wfc2 = (const float*)d_in[11];
    const float* bfc2 = (const float*)d_in[12];
    const float* Wfc  = (const float*)d_in[13];
    const float* bfc  = (const float*)d_in[14];
    float* out = (float*)d_out;

    lstm3_kernel<<<dim3(BB), dim3(256), 0, stream>>>(
        x, Wih1, Whh1, bih1, bhh1, Wih2, Whh2, bih2, bhh2,
        Wfc1, bfc1, Wfc2, bfc2, Wfc, bfc, out);
}